// Round 1
// baseline (7433.087 us; speedup 1.0000x reference)
//
#include <hip/hip_runtime.h>
#include <hip/hip_bf16.h>
#include <stdint.h>

#define SS 4096
#define HH 1024
#define EE 512
#define NB 128
#define SENT 0xFFFFFFFFu

__device__ __forceinline__ uint32_t ld_agent_u32(const uint32_t* p) {
  return __hip_atomic_load((uint32_t*)p, __ATOMIC_RELAXED, __HIP_MEMORY_SCOPE_AGENT);
}
__device__ __forceinline__ void st_agent_f32(float* p, float v) {
  __hip_atomic_store(p, v, __ATOMIC_RELAXED, __HIP_MEMORY_SCOPE_AGENT);
}

// x_proj[t][j] = dot(emb[tok[t]], W_in[j]) + b_in[j]
// 64x64 tile per block, K-chunks of 32, 256 threads (16x16, 4x4 microtile).
__global__ __launch_bounds__(256) void xproj_kernel(
    const int* __restrict__ tok, const float* __restrict__ emb,
    const float* __restrict__ Win, const float* __restrict__ bin,
    float* __restrict__ xp)
{
  __shared__ float As[64][33];
  __shared__ float Bs[64][33];
  const int t0 = blockIdx.x * 64;
  const int j0 = blockIdx.y * 64;
  const int tid = threadIdx.x;
  const int lr  = tid >> 3;         // 0..31
  const int lk4 = (tid & 7) << 2;   // 0,4,...,28
  const int tx = tid & 15, ty = tid >> 4;

  const int ta = tok[t0 + lr];
  const int tb = tok[t0 + lr + 32];
  const float* embA = emb + (size_t)ta * EE;
  const float* embB = emb + (size_t)tb * EE;
  const float* winA = Win + (size_t)(j0 + lr) * EE;
  const float* winB = Win + (size_t)(j0 + lr + 32) * EE;

  float acc[4][4];
#pragma unroll
  for (int i = 0; i < 4; ++i)
#pragma unroll
    for (int j = 0; j < 4; ++j) acc[i][j] = 0.f;

  for (int kc = 0; kc < EE; kc += 32) {
    float4 a0 = *(const float4*)(embA + kc + lk4);
    float4 a1 = *(const float4*)(embB + kc + lk4);
    float4 b0 = *(const float4*)(winA + kc + lk4);
    float4 b1 = *(const float4*)(winB + kc + lk4);
    As[lr][lk4 + 0] = a0.x; As[lr][lk4 + 1] = a0.y; As[lr][lk4 + 2] = a0.z; As[lr][lk4 + 3] = a0.w;
    As[lr + 32][lk4 + 0] = a1.x; As[lr + 32][lk4 + 1] = a1.y; As[lr + 32][lk4 + 2] = a1.z; As[lr + 32][lk4 + 3] = a1.w;
    Bs[lr][lk4 + 0] = b0.x; Bs[lr][lk4 + 1] = b0.y; Bs[lr][lk4 + 2] = b0.z; Bs[lr][lk4 + 3] = b0.w;
    Bs[lr + 32][lk4 + 0] = b1.x; Bs[lr + 32][lk4 + 1] = b1.y; Bs[lr + 32][lk4 + 2] = b1.z; Bs[lr + 32][lk4 + 3] = b1.w;
    __syncthreads();
#pragma unroll
    for (int k = 0; k < 32; ++k) {
      float av[4], bv[4];
#pragma unroll
      for (int i = 0; i < 4; ++i) av[i] = As[ty * 4 + i][k];
#pragma unroll
      for (int j = 0; j < 4; ++j) bv[j] = Bs[tx * 4 + j][k];
#pragma unroll
      for (int i = 0; i < 4; ++i)
#pragma unroll
        for (int j = 0; j < 4; ++j) acc[i][j] = fmaf(av[i], bv[j], acc[i][j]);
    }
    __syncthreads();
  }

  float bv[4];
#pragma unroll
  for (int j = 0; j < 4; ++j) bv[j] = bin[j0 + tx * 4 + j];
#pragma unroll
  for (int i = 0; i < 4; ++i) {
    float4 o;
    o.x = acc[i][0] + bv[0]; o.y = acc[i][1] + bv[1];
    o.z = acc[i][2] + bv[2]; o.w = acc[i][3] + bv[3];
    *(float4*)(xp + (size_t)(t0 + ty * 4 + i) * HH + j0 + tx * 4) = o;
  }
}

// Persistent recurrence: 128 blocks x 256 threads. Block b owns rows
// [8b, 8b+8) of W_h, held in registers (wave w: rows 8b+2w, 8b+2w+1;
// lane l holds columns l+64k, k=0..15). hist slot t holds h_{t+1};
// values double as ready-flags (sentinel 0xFFFFFFFF = NaN, impossible
// for a tanh output). Agent-scope atomics for cross-XCD visibility.
__global__ __launch_bounds__(256) void rnn_kernel(
    const float* __restrict__ Wh, const float* __restrict__ bh,
    const float* __restrict__ xp, float* __restrict__ hist,
    const float* __restrict__ Wout, const float* __restrict__ bout,
    float* __restrict__ out)
{
  const int blk = blockIdx.x;
  const int tid = threadIdx.x;
  const int w = tid >> 6;
  const int l = tid & 63;
  const int rowA = blk * 8 + 2 * w;
  const int rowB = rowA + 1;

  float wA[16], wB[16];
#pragma unroll
  for (int k = 0; k < 16; ++k) {
    wA[k] = Wh[(size_t)rowA * HH + l + 64 * k];
    wB[k] = Wh[(size_t)rowB * HH + l + 64 * k];
  }
  const float bhA = bh[rowA];
  const float bhB = bh[rowB];

  for (int t = 0; t < SS; ++t) {
    float xA = xp[(size_t)t * HH + rowA];   // issued before poll; latency hides
    float xB = xp[(size_t)t * HH + rowB];
    float acc0 = 0.f, acc1 = 0.f;
    if (t > 0) {
      const uint32_t* hs = (const uint32_t*)(hist + (size_t)(t - 1) * HH);
      uint32_t hv[16];
      for (;;) {
        int ok = 1;
#pragma unroll
        for (int k = 0; k < 16; ++k) {
          hv[k] = ld_agent_u32(hs + l + 64 * k);
          ok &= (hv[k] != SENT);
        }
        if (__all(ok)) break;
      }
#pragma unroll
      for (int k = 0; k < 16; ++k) {
        float h = __uint_as_float(hv[k]);
        acc0 = fmaf(wA[k], h, acc0);
        acc1 = fmaf(wB[k], h, acc1);
      }
    }
#pragma unroll
    for (int off = 1; off < 64; off <<= 1) {
      acc0 += __shfl_xor(acc0, off);
      acc1 += __shfl_xor(acc1, off);
    }
    if (l < 2) {
      float pre = (l == 0) ? (acc0 + xA + bhA) : (acc1 + xB + bhB);
      float hval = tanhf(pre);
      st_agent_f32(hist + (size_t)t * HH + rowA + l, hval);
    }
  }

  // Epilogue: block 0, wave 0 computes the classifier head + log_softmax.
  if (blk == 0 && w == 0) {
    const uint32_t* hs = (const uint32_t*)(hist + (size_t)(SS - 1) * HH);
    uint32_t hv[16];
    for (;;) {
      int ok = 1;
#pragma unroll
      for (int k = 0; k < 16; ++k) {
        hv[k] = ld_agent_u32(hs + l + 64 * k);
        ok &= (hv[k] != SENT);
      }
      if (__all(ok)) break;
    }
    float c0 = 0.f, c1 = 0.f;
#pragma unroll
    for (int k = 0; k < 16; ++k) {
      float h = __uint_as_float(hv[k]);
      c0 = fmaf(Wout[l + 64 * k], h, c0);
      c1 = fmaf(Wout[HH + l + 64 * k], h, c1);
    }
#pragma unroll
    for (int off = 1; off < 64; off <<= 1) {
      c0 += __shfl_xor(c0, off);
      c1 += __shfl_xor(c1, off);
    }
    if (l == 0) {
      float s0 = c0 + bout[0];
      float s1 = c1 + bout[1];
      float m = fmaxf(s0, s1);
      float lse = m + logf(expf(s0 - m) + expf(s1 - m));
      out[0] = s0 - lse;
      out[1] = s1 - lse;
    }
  }
}

extern "C" void kernel_launch(void* const* d_in, const int* in_sizes, int n_in,
                              void* d_out, int out_size, void* d_ws, size_t ws_size,
                              hipStream_t stream)
{
  const int*   tok  = (const int*)  d_in[0];
  const float* emb  = (const float*)d_in[1];
  const float* Win  = (const float*)d_in[2];
  const float* bin  = (const float*)d_in[3];
  const float* Wh   = (const float*)d_in[4];
  const float* bh   = (const float*)d_in[5];
  const float* Wout = (const float*)d_in[6];
  const float* bout = (const float*)d_in[7];

  const size_t need = (size_t)2 * SS * HH * sizeof(float);  // xp + hist = 32 MB
  if (ws_size < need) return;  // if this trips, the failed bench tells us ws_size

  float* xp   = (float*)d_ws;
  float* hist = xp + (size_t)SS * HH;

  // Sentinel-fill the h history each launch (ws is not re-poisoned between
  // replays; 0xFF bytes = NaN bit pattern = "not yet written").
  hipMemsetAsync(hist, 0xFF, (size_t)SS * HH * sizeof(float), stream);

  xproj_kernel<<<dim3(SS / 64, HH / 64), 256, 0, stream>>>(tok, emb, Win, bin, xp);
  rnn_kernel<<<NB, 256, 0, stream>>>(Wh, bh, xp, hist, Wout, bout, (float*)d_out);
}